// Round 8
// baseline (35.097 us; speedup 1.0000x reference)
//
#include <hip/hip_runtime.h>

#define B_ 64
#define M_ 4096
#define D_ 128
#define O_ 16

typedef __bf16 bf16x8 __attribute__((ext_vector_type(8)));
typedef float  f32x4  __attribute__((ext_vector_type(4)));

// Pass 1: u[b,k,o] = sum_d x1[b,d]*W[o,d,k] + v2[o,k], emitted as bf16 in
// MFMA B-fragment order: lane = kgroup*16 + o, k = kb*32 + kgroup*8 + e.
//         c[b,o] = x1[b].v1[o] + bias[o]
__global__ __launch_bounds__(128) void prep_kernel(
    const float* __restrict__ x1, const float* __restrict__ W,
    const float* __restrict__ V, const float* __restrict__ bias,
    __bf16* __restrict__ ub, float* __restrict__ c)
{
    const int o = blockIdx.x;   // [0,16)
    const int b = blockIdx.y;   // [0,64)
    const int k = threadIdx.x;  // [0,128)
    __shared__ float x1s[D_];
    __shared__ float red[2];
    x1s[k] = x1[b * D_ + k];
    __syncthreads();

    const float* Wo = W + o * D_ * D_;
    float acc = 0.f;
    #pragma unroll 8
    for (int d = 0; d < D_; ++d)
        acc = fmaf(x1s[d], Wo[d * D_ + k], acc);   // coalesced over k

    const float uval = acc + V[o * 2 * D_ + D_ + k];   // + v2[o,k]
    const int e  = k & 7;
    const int g  = (k >> 3) & 3;
    const int kb = k >> 5;
    ub[(size_t)b * 2048 + kb * 512 + g * 128 + o * 8 + e] = (__bf16)uval;

    float p = x1s[k] * V[o * 2 * D_ + k];
    #pragma unroll
    for (int off = 32; off; off >>= 1) p += __shfl_down(p, off, 64);
    if ((k & 63) == 0) red[k >> 6] = p;
    __syncthreads();
    if (k == 0) c[b * O_ + o] = red[0] + red[1] + bias[o];
}

// Pass 2: out[b,m,o] = relu( x2[b,m,:] x u[b,:,:] + c[b,o] ) via MFMA.
// 256-thr blocks (8 block-slots/CU suffice) with VGPR<=64 via 2-deep kb
// register pipeline -> 8 blocks/CU = 32 waves/CU = 100% wave residency.
__global__ __launch_bounds__(256, 8) void fused_kernel(
    const float* __restrict__ x2, const __bf16* __restrict__ ub,
    const float* __restrict__ c, float* __restrict__ out)
{
    const int b = blockIdx.y;
    const int t = threadIdx.x;
    const int wave = t >> 6, lane = t & 63;
    const int rc = lane & 15;          // A-row / C-col (o)
    const int g  = lane >> 4;          // k-group

    // B-fragments straight from global: 1KB/wave-instr coalesced, L2-hot.
    const bf16x8* uf = (const bf16x8*)(ub + (size_t)b * 2048);
    bf16x8 bfrag[4];
    #pragma unroll
    for (int kb = 0; kb < 4; ++kb) bfrag[kb] = uf[kb * 64 + lane];
    const float cv = c[b * O_ + rc];

    const int m_base = blockIdx.x * 128 + wave * 32;

    #pragma unroll
    for (int tt = 0; tt < 2; ++tt) {
        const int m0 = m_base + tt * 16;
        // lane reads x2[b][m0+rc][kb*32 + g*8 .. +7]; per instr the wave
        // covers 16 rows, full-line utilization across the kb loop.
        const float4* ap = (const float4*)(x2 + ((size_t)b * M_ + m0 + rc) * D_) + g * 2;

        float4 c0 = ap[0], c1 = ap[1];     // kb=0 in flight
        f32x4 acc = {cv, cv, cv, cv};
        #pragma unroll
        for (int kb = 0; kb < 4; ++kb) {
            float4 n0, n1;
            if (kb < 3) { n0 = ap[(kb + 1) * 8]; n1 = ap[(kb + 1) * 8 + 1]; }
            bf16x8 af;
            af[0] = (__bf16)c0.x; af[1] = (__bf16)c0.y;
            af[2] = (__bf16)c0.z; af[3] = (__bf16)c0.w;
            af[4] = (__bf16)c1.x; af[5] = (__bf16)c1.y;
            af[6] = (__bf16)c1.z; af[7] = (__bf16)c1.w;
            acc = __builtin_amdgcn_mfma_f32_16x16x32_bf16(af, bfrag[kb], acc, 0, 0, 0);
            c0 = n0; c1 = n1;
        }

        // C/D: col = lane&15 (=o), row = g*4 + i  (verified m89/m91)
        float* op = out + ((size_t)b * M_ + m0) * O_ + rc;
        #pragma unroll
        for (int i = 0; i < 4; ++i)
            op[(g * 4 + i) * O_] = fmaxf(acc[i], 0.f);
    }
}

extern "C" void kernel_launch(void* const* d_in, const int* in_sizes, int n_in,
                              void* d_out, int out_size, void* d_ws, size_t ws_size,
                              hipStream_t stream) {
    const float* x1   = (const float*)d_in[0];
    const float* x2   = (const float*)d_in[1];
    const float* W    = (const float*)d_in[2];
    const float* V    = (const float*)d_in[3];
    const float* bias = (const float*)d_in[4];
    float* out = (float*)d_out;

    __bf16* ubf = (__bf16*)d_ws;                           // 64*2048 bf16 = 256 KB
    float*  c   = (float*)((char*)d_ws + (size_t)B_ * 2048 * sizeof(__bf16));

    prep_kernel<<<dim3(O_, B_), 128, 0, stream>>>(x1, W, V, bias, ubf, c);
    fused_kernel<<<dim3(M_ / 128, B_), 256, 0, stream>>>(x2, ubf, c, out);
}